// Round 3
// baseline (719.172 us; speedup 1.0000x reference)
//
#include <hip/hip_runtime.h>

// radius-graph edges, N=8192 points in 2D, periodic box L=1.
// d_out (fp32, concatenated):
//   [0 .. N*N)      dist[i][j] = || minimum_image(x[j] - x[i]) ||
//   [N*N .. 2*N*N)  within[i][j] = (dist < 0.1) && (i != j)  as 0.0/1.0
//
// Write-BW-bound: 536 MB of output stores; x (64 KB) is cache-resident.
// This rev: 8 columns/thread + nontemporal dwordx4 stores (output is
// write-once, never re-read -> don't retain in L2).

constexpr int   N  = 8192;
constexpr float R0 = 0.1f;

typedef float f32x4 __attribute__((ext_vector_type(4)));

__global__ __launch_bounds__(256)
void radiusgraph_kernel(const float* __restrict__ x,
                        float* __restrict__ dist,
                        float* __restrict__ mask) {
    const int i  = blockIdx.y;                               // row
    const int j0 = (blockIdx.x * 256 + threadIdx.x) * 8;     // 8 columns per thread

    // row point: uniform per block -> scalar loads
    const float xix = x[2 * (size_t)i];
    const float xiy = x[2 * (size_t)i + 1];

    const size_t rowbase = (size_t)i * N;

#pragma unroll
    for (int h = 0; h < 2; ++h) {
        const int j = j0 + h * 4;

        // 4 consecutive float2 points = two dwordx4 loads (L1/L2-hit)
        const f32x4 a = *reinterpret_cast<const f32x4*>(x + 2 * (size_t)j);
        const f32x4 b = *reinterpret_cast<const f32x4*>(x + 2 * (size_t)j + 4);

        const float xs[4] = {a.x, a.z, b.x, b.z};
        const float ys[4] = {a.y, a.w, b.y, b.w};

        f32x4 dout, mout;
#pragma unroll
        for (int k = 0; k < 4; ++k) {
            float dx = xs[k] - xix;
            float dy = ys[k] - xiy;
            dx -= rintf(dx);      // minimum image, L=1 (v_rndne_f32 == jnp.round)
            dy -= rintf(dy);
            const float d = sqrtf(dx * dx + dy * dy);
            dout[k] = d;
            mout[k] = (d < R0 && (j + k) != i) ? 1.0f : 0.0f;
        }

        __builtin_nontemporal_store(dout, reinterpret_cast<f32x4*>(dist + rowbase + j));
        __builtin_nontemporal_store(mout, reinterpret_cast<f32x4*>(mask + rowbase + j));
    }
}

extern "C" void kernel_launch(void* const* d_in, const int* in_sizes, int n_in,
                              void* d_out, int out_size, void* d_ws, size_t ws_size,
                              hipStream_t stream) {
    const float* x = (const float*)d_in[0];
    float* out  = (float*)d_out;
    float* dist = out;
    float* mask = out + (size_t)N * N;

    dim3 grid(N / (256 * 8), N);   // (4, 8192) blocks, 256 thr
    radiusgraph_kernel<<<grid, dim3(256), 0, stream>>>(x, dist, mask);
}

// Round 6
// 513.863 us; speedup vs baseline: 1.3995x; 1.3995x over previous
//
#include <hip/hip_runtime.h>

// radius-graph edges, N=8192 points in 2D, periodic box L=1.
// d_out (fp32, concatenated):
//   [0 .. N*N)      dist[i][j] = || minimum_image(x[j] - x[i]) ||
//   [N*N .. 2*N*N)  within[i][j] = (dist < 0.1) && (i != j)  as 0.0/1.0
//
// Write-BW-bound: 536 MB of output stores; x (64 KB) cache-resident.
// Round-3 lesson: nontemporal + interleaved half-line stores regressed 507->719us
// (partial 64B-line writes can't merge when L2 retention is bypassed).
// This rev: plain stores; 8 cols/thread split as two 1024-col halves so every
// dwordx4 store instruction is a dense, wave-contiguous 1 KB burst.

constexpr int   N  = 8192;
constexpr float R0 = 0.1f;

typedef float f32x4 __attribute__((ext_vector_type(4)));

__global__ __launch_bounds__(256)
void radiusgraph_kernel(const float* __restrict__ x,
                        float* __restrict__ dist,
                        float* __restrict__ mask) {
    const int i    = blockIdx.y;                 // row (uniform per block)
    const int jblk = blockIdx.x * 2048;          // 2048 cols per block

    // row point: block-uniform -> compiler emits scalar loads
    const float xix = x[2 * (size_t)i];
    const float xiy = x[2 * (size_t)i + 1];

    const size_t rowbase = (size_t)i * N;

#pragma unroll
    for (int h = 0; h < 2; ++h) {
        const int j = jblk + h * 1024 + threadIdx.x * 4;   // wave-contiguous 4-col chunk

        // 4 consecutive float2 points = two dwordx4 loads (L1/L2-hit)
        const f32x4 a = *reinterpret_cast<const f32x4*>(x + 2 * (size_t)j);
        const f32x4 b = *reinterpret_cast<const f32x4*>(x + 2 * (size_t)j + 4);

        const float xs[4] = {a.x, a.z, b.x, b.z};
        const float ys[4] = {a.y, a.w, b.y, b.w};

        f32x4 dout, mout;
#pragma unroll
        for (int k = 0; k < 4; ++k) {
            float dx = xs[k] - xix;
            float dy = ys[k] - xiy;
            dx -= rintf(dx);      // minimum image, L=1 (v_rndne_f32 == jnp.round)
            dy -= rintf(dy);
            const float d = sqrtf(dx * dx + dy * dy);
            dout[k] = d;
            mout[k] = (d < R0 && (j + k) != i) ? 1.0f : 0.0f;
        }

        // dense wave-contiguous 1 KB bursts (lane t -> bytes [16t,16t+16))
        *reinterpret_cast<f32x4*>(dist + rowbase + j) = dout;
        *reinterpret_cast<f32x4*>(mask + rowbase + j) = mout;
    }
}

extern "C" void kernel_launch(void* const* d_in, const int* in_sizes, int n_in,
                              void* d_out, int out_size, void* d_ws, size_t ws_size,
                              hipStream_t stream) {
    const float* x = (const float*)d_in[0];
    float* out  = (float*)d_out;
    float* dist = out;
    float* mask = out + (size_t)N * N;

    dim3 grid(N / 2048, N);      // (4, 8192) blocks, 256 thr
    radiusgraph_kernel<<<grid, dim3(256), 0, stream>>>(x, dist, mask);
}